// Round 1
// baseline (254.893 us; speedup 1.0000x reference)
//
#include <hip/hip_runtime.h>

typedef __attribute__((ext_vector_type(8))) short bf16x8;
typedef __attribute__((ext_vector_type(4))) float f32x4;

#define MFMA16(A, B, C) __builtin_amdgcn_mfma_f32_16x16x32_bf16(A, B, C, 0, 0, 0)

__device__ __forceinline__ unsigned short f2bf(float f) {
    unsigned int u = __float_as_uint(f);
    u += 0x7fffu + ((u >> 16) & 1u);
    return (unsigned short)(u >> 16);
}
__device__ __forceinline__ float bf2f(unsigned short h) {
    return __uint_as_float(((unsigned int)h) << 16);
}

__device__ __forceinline__ void gload_lds16(const void* g, void* l) {
    __builtin_amdgcn_global_load_lds(
        (__attribute__((address_space(1))) unsigned int*)g,
        (__attribute__((address_space(3))) unsigned int*)l, 16, 0, 0);
}

// ---------------------------------------------------------------- converts
__global__ void cvt_kernel(const float* __restrict__ in, unsigned short* __restrict__ out, int n4) {
    const int i = blockIdx.x * 256 + threadIdx.x;
    if (i >= n4) return;
    const float4 v = ((const float4*)in)[i];
    unsigned int lo = (unsigned int)f2bf(v.x) | ((unsigned int)f2bf(v.y) << 16);
    unsigned int hi = (unsigned int)f2bf(v.z) | ((unsigned int)f2bf(v.w) << 16);
    uint2 o; o.x = lo; o.y = hi;
    ((uint2*)out)[i] = o;
}

// ---------------------------------------------------------------- doc starts
__global__ void docstart_kernel(const int* __restrict__ sid, int* __restrict__ ds) {
    const int i = blockIdx.x * 256 + threadIdx.x; // 0..4095
    const int b = i >> 11, s = i & 2047;
    const int* row = sid + b * 2048;
    const int v = row[s];
    int lo = 0, hi = s;
    while (lo < hi) { const int mid = (lo + hi) >> 1; if (row[mid] < v) lo = mid + 1; else hi = mid; }
    ds[i] = lo;
}

// ---------------------------------------------------------------- bt-GEMM (m97 structure)
// C[m][n] = sum_k A[m][k] * B[n][k], A:(M,K) bf16 row-major, B:(N,K) bf16 row-major.
// 128x128 tile, BK=32, 256 threads (2x2 waves, each 64x64 = 4x4 frags of 16x16x32).
template <int EPI>
__global__ __launch_bounds__(256) void gemm_bt(
    const unsigned short* __restrict__ A,
    const unsigned short* __restrict__ B,
    int K, int N,
    unsigned short* __restrict__ oq,
    unsigned short* __restrict__ ok,
    unsigned short* __restrict__ ov,
    float* __restrict__ of)
{
    __shared__ __align__(16) unsigned short sA[128 * 32];
    __shared__ __align__(16) unsigned short sB[128 * 32];
    const int tid = threadIdx.x;
    const int lane = tid & 63, wave = tid >> 6;
    const int wr = wave >> 1, wc = wave & 1;
    const int lr = lane & 15, lc = lane >> 4;
    const int m0 = blockIdx.y * 128, n0 = blockIdx.x * 128;

    f32x4 acc[4][4];
#pragma unroll
    for (int i = 0; i < 4; i++)
#pragma unroll
        for (int j = 0; j < 4; j++) acc[i][j] = (f32x4){0.f, 0.f, 0.f, 0.f};

    const int u0 = tid, u1 = tid + 256;
    for (int k0 = 0; k0 < K; k0 += 32) {
        __syncthreads();
        gload_lds16(A + (size_t)(m0 + (u0 >> 2)) * K + k0 + (u0 & 3) * 8, &sA[u0 * 8]);
        gload_lds16(A + (size_t)(m0 + (u1 >> 2)) * K + k0 + (u1 & 3) * 8, &sA[u1 * 8]);
        gload_lds16(B + (size_t)(n0 + (u0 >> 2)) * K + k0 + (u0 & 3) * 8, &sB[u0 * 8]);
        gload_lds16(B + (size_t)(n0 + (u1 >> 2)) * K + k0 + (u1 & 3) * 8, &sB[u1 * 8]);
        __syncthreads();
        bf16x8 af[4], bfv[4];
#pragma unroll
        for (int i = 0; i < 4; i++) {
            af[i]  = *(const bf16x8*)&sA[(wr * 64 + i * 16 + lr) * 32 + lc * 8];
            bfv[i] = *(const bf16x8*)&sB[(wc * 64 + i * 16 + lr) * 32 + lc * 8];
        }
#pragma unroll
        for (int i = 0; i < 4; i++)
#pragma unroll
            for (int j = 0; j < 4; j++) acc[i][j] = MFMA16(af[i], bfv[j], acc[i][j]);
    }

    if (EPI == 0) {
        // scatter into Q:(B,32,S,64), K/V:(B,8,S,64) bf16
#pragma unroll
        for (int i = 0; i < 4; i++) {
#pragma unroll
            for (int j = 0; j < 4; j++) {
                const int n = n0 + wc * 64 + j * 16 + lr;
                const int d = n & 63;
#pragma unroll
                for (int r = 0; r < 4; r++) {
                    const int m = m0 + wr * 64 + i * 16 + lc * 4 + r;
                    const int bb = m >> 11, s = m & 2047;
                    const unsigned short val = f2bf(acc[i][j][r]);
                    if (n < 2048) {
                        const int hh = n >> 6;
                        oq[((((size_t)bb * 32 + hh) * 2048 + s) << 6) + d] = val;
                    } else if (n < 2560) {
                        const int hh = (n >> 6) - 32;
                        ok[((((size_t)bb * 8 + hh) * 2048 + s) << 6) + d] = val;
                    } else {
                        const int hh = (n >> 6) - 40;
                        ov[((((size_t)bb * 8 + hh) * 2048 + s) << 6) + d] = val;
                    }
                }
            }
        }
    } else {
#pragma unroll
        for (int i = 0; i < 4; i++)
#pragma unroll
            for (int j = 0; j < 4; j++)
#pragma unroll
                for (int r = 0; r < 4; r++) {
                    const int m = m0 + wr * 64 + i * 16 + lc * 4 + r;
                    const int n = n0 + wc * 64 + j * 16 + lr;
                    of[(size_t)m * N + n] = acc[i][j][r];
                }
    }
}

// ---------------------------------------------------------------- RoPE (in-place on Q and K, bf16)
__global__ void rope_kernel(unsigned short* __restrict__ Qb,
                            unsigned short* __restrict__ Kb,
                            const float* __restrict__ fc)
{
    const int NQ = 2 * 32 * 2048 * 32; // 4194304 pairs
    int i = blockIdx.x * 256 + threadIdx.x;
    unsigned short* base;
    if (i < NQ) base = Qb;
    else { base = Kb; i -= NQ; }
    const int p = i & 31, s = (i >> 5) & 2047, bh = i >> 16;
    const size_t off = (((size_t)bh * 2048 + s) << 6) + p * 2;
    const unsigned int w = *(const unsigned int*)&base[off];
    const float t0 = bf2f((unsigned short)(w & 0xffffu));
    const float t1 = bf2f((unsigned short)(w >> 16));
    const float c = fc[(s * 32 + p) * 2], sn = fc[(s * 32 + p) * 2 + 1];
    const unsigned short o0 = f2bf(t0 * c - t1 * sn);
    const unsigned short o1 = f2bf(t0 * sn + t1 * c);
    *(unsigned int*)&base[off] = (unsigned int)o0 | ((unsigned int)o1 << 16);
}

// ---------------------------------------------------------------- flash attention
// grid: (qtile 32, head 32, batch 2); block 256 = 4 waves; each wave owns 16 q-rows.
__global__ __launch_bounds__(256) void attn_kernel(
    const unsigned short* __restrict__ Q,
    const unsigned short* __restrict__ K,
    const unsigned short* __restrict__ V,
    const int* __restrict__ dstart,
    unsigned short* __restrict__ AO)
{
    const int qt = blockIdx.x, h = blockIdx.y, b = blockIdx.z;
    const int kvh = h >> 2;
    const int tid = threadIdx.x, lane = tid & 63, wave = tid >> 6;
    const int lr = lane & 15, lc = lane >> 4;
    const int q0 = qt * 64;
    const int qw = q0 + wave * 16;

    __shared__ __align__(16) unsigned short sK[64][72];
    __shared__ __align__(16) unsigned short sVt[64][72];
    __shared__ __align__(16) unsigned short sP[4][16][72];

    const unsigned short* Qh = Q + (((size_t)b * 32 + h) * 2048) * 64;
    const unsigned short* Kh = K + (((size_t)b * 8 + kvh) * 2048) * 64;
    const unsigned short* Vh = V + (((size_t)b * 8 + kvh) * 2048) * 64;

    const bf16x8 qf0 = *(const bf16x8*)&Qh[(size_t)(qw + lr) * 64 + lc * 8];
    const bf16x8 qf1 = *(const bf16x8*)&Qh[(size_t)(qw + lr) * 64 + 32 + lc * 8];

    int dsr[4];
#pragma unroll
    for (int r = 0; r < 4; r++) dsr[r] = dstart[b * 2048 + qw + lc * 4 + r];
    const int ds_wmin = dstart[b * 2048 + qw];
    const int t0 = dstart[b * 2048 + q0] & ~63;

    float mrow[4] = {-1e30f, -1e30f, -1e30f, -1e30f};
    float lrow[4] = {0.f, 0.f, 0.f, 0.f};
    f32x4 oacc[4];
#pragma unroll
    for (int j = 0; j < 4; j++) oacc[j] = (f32x4){0.f, 0.f, 0.f, 0.f};

    for (int t = t0; t < q0 + 64; t += 64) {
        __syncthreads();
        {
            int u = tid;
            int kr = u >> 3, d8 = (u & 7) * 8;
            *(uint4*)&sK[kr][d8] = *(const uint4*)&Kh[(size_t)(t + kr) * 64 + d8];
            uint4 vv = *(const uint4*)&Vh[(size_t)(t + kr) * 64 + d8];
            const unsigned short* pv = (const unsigned short*)&vv;
#pragma unroll
            for (int e = 0; e < 8; e++) sVt[d8 + e][kr] = pv[e];
            u = tid + 256;
            kr = u >> 3; d8 = (u & 7) * 8;
            *(uint4*)&sK[kr][d8] = *(const uint4*)&Kh[(size_t)(t + kr) * 64 + d8];
            vv = *(const uint4*)&Vh[(size_t)(t + kr) * 64 + d8];
            const unsigned short* pv2 = (const unsigned short*)&vv;
#pragma unroll
            for (int e = 0; e < 8; e++) sVt[d8 + e][kr] = pv2[e];
        }
        __syncthreads();
        if (t > qw + 15 || t + 63 < ds_wmin) continue; // wave-uniform skip

        // QK^T: S[q][k], q = rows of this wave, k = t..t+63
        f32x4 sc[4];
#pragma unroll
        for (int kk = 0; kk < 4; kk++) {
            const bf16x8 kf0 = *(const bf16x8*)&sK[kk * 16 + lr][lc * 8];
            const bf16x8 kf1 = *(const bf16x8*)&sK[kk * 16 + lr][32 + lc * 8];
            f32x4 a = (f32x4){0.f, 0.f, 0.f, 0.f};
            a = MFMA16(qf0, kf0, a);
            a = MFMA16(qf1, kf1, a);
            sc[kk] = a;
        }
        // mask + scale
#pragma unroll
        for (int kk = 0; kk < 4; kk++) {
            const int kpos = t + kk * 16 + lr;
#pragma unroll
            for (int r = 0; r < 4; r++) {
                const int qr = qw + lc * 4 + r;
                const bool ok = (kpos <= qr) && (kpos >= dsr[r]);
                sc[kk][r] = ok ? sc[kk][r] * 0.125f : -3e38f;
            }
        }
        // online softmax
        float corr[4], mnew[4];
#pragma unroll
        for (int r = 0; r < 4; r++) {
            float v = fmaxf(fmaxf(sc[0][r], sc[1][r]), fmaxf(sc[2][r], sc[3][r]));
            v = fmaxf(v, __shfl_xor(v, 1));
            v = fmaxf(v, __shfl_xor(v, 2));
            v = fmaxf(v, __shfl_xor(v, 4));
            v = fmaxf(v, __shfl_xor(v, 8));
            mnew[r] = fmaxf(mrow[r], v);
            corr[r] = __expf(mrow[r] - mnew[r]);
            mrow[r] = mnew[r];
        }
#pragma unroll
        for (int kk = 0; kk < 4; kk++)
#pragma unroll
            for (int r = 0; r < 4; r++) sc[kk][r] = __expf(sc[kk][r] - mnew[r]);
#pragma unroll
        for (int r = 0; r < 4; r++) {
            float s = sc[0][r] + sc[1][r] + sc[2][r] + sc[3][r];
            s += __shfl_xor(s, 1);
            s += __shfl_xor(s, 2);
            s += __shfl_xor(s, 4);
            s += __shfl_xor(s, 8);
            lrow[r] = lrow[r] * corr[r] + s;
#pragma unroll
            for (int j = 0; j < 4; j++) oacc[j][r] *= corr[r];
        }
        // P -> LDS (C-layout) -> A-frag layout
#pragma unroll
        for (int kk = 0; kk < 4; kk++)
#pragma unroll
            for (int r = 0; r < 4; r++) sP[wave][lc * 4 + r][kk * 16 + lr] = f2bf(sc[kk][r]);
        asm volatile("s_waitcnt lgkmcnt(0)" ::: "memory");
        const bf16x8 pf0 = *(const bf16x8*)&sP[wave][lr][lc * 8];
        const bf16x8 pf1 = *(const bf16x8*)&sP[wave][lr][32 + lc * 8];
        // PV: O[q][d] += P[q][k] * V[k][d]  (B-frag from V^T tile)
#pragma unroll
        for (int j = 0; j < 4; j++) {
            const bf16x8 v0 = *(const bf16x8*)&sVt[j * 16 + lr][lc * 8];
            const bf16x8 v1 = *(const bf16x8*)&sVt[j * 16 + lr][32 + lc * 8];
            oacc[j] = MFMA16(pf0, v0, oacc[j]);
            oacc[j] = MFMA16(pf1, v1, oacc[j]);
        }
    }

    // epilogue: AO (B, S, H*64) bf16
#pragma unroll
    for (int j = 0; j < 4; j++)
#pragma unroll
        for (int r = 0; r < 4; r++) {
            const int qg = qw + lc * 4 + r;
            const float v = oacc[j][r] / lrow[r];
            AO[((size_t)b * 2048 + qg) * 2048 + h * 64 + j * 16 + lr] = f2bf(v);
        }
}

// ---------------------------------------------------------------- host
extern "C" void kernel_launch(void* const* d_in, const int* in_sizes, int n_in,
                              void* d_out, int out_size, void* d_ws, size_t ws_size,
                              hipStream_t stream) {
    const float* x  = (const float*)d_in[0];
    const float* fc = (const float*)d_in[1];
    const int* sid  = (const int*)d_in[2];
    const float* wq = (const float*)d_in[3];
    const float* wk = (const float*)d_in[4];
    const float* wv = (const float*)d_in[5];
    const float* wo = (const float*)d_in[6];
    float* out = (float*)d_out;

    unsigned short* xb   = (unsigned short*)d_ws;                    // 4096x2048
    unsigned short* wqkv = xb + (size_t)4096 * 2048;                 // 3072x2048
    unsigned short* wob  = wqkv + (size_t)3072 * 2048;               // 2048x2048
    unsigned short* Qb   = wob + (size_t)2048 * 2048;                // (2,32,2048,64)
    unsigned short* Kb   = Qb + (size_t)2 * 32 * 2048 * 64;          // (2,8,2048,64)
    unsigned short* Vb   = Kb + (size_t)2 * 8 * 2048 * 64;           // (2,8,2048,64)
    unsigned short* AO   = Vb + (size_t)2 * 8 * 2048 * 64;           // (2,2048,2048)
    int* dstart = (int*)(AO + (size_t)4096 * 2048);                  // 4096

    cvt_kernel<<<8192, 256, 0, stream>>>(x, xb, 2097152);
    cvt_kernel<<<4096, 256, 0, stream>>>(wq, wqkv, 1048576);
    cvt_kernel<<<1024, 256, 0, stream>>>(wk, wqkv + (size_t)2048 * 2048, 262144);
    cvt_kernel<<<1024, 256, 0, stream>>>(wv, wqkv + (size_t)2560 * 2048, 262144);
    cvt_kernel<<<4096, 256, 0, stream>>>(wo, wob, 1048576);
    docstart_kernel<<<16, 256, 0, stream>>>(sid, dstart);
    gemm_bt<0><<<dim3(24, 32), 256, 0, stream>>>(xb, wqkv, 2048, 3072, Qb, Kb, Vb, nullptr);
    rope_kernel<<<20480, 256, 0, stream>>>(Qb, Kb, fc);
    attn_kernel<<<dim3(32, 32, 2), 256, 0, stream>>>(Qb, Kb, Vb, dstart, AO);
    gemm_bt<1><<<dim3(16, 32), 256, 0, stream>>>(AO, wob, 2048, 2048, nullptr, nullptr, nullptr, out);
}

// Round 4
// 221.072 us; speedup vs baseline: 1.1530x; 1.1530x over previous
//
#include <hip/hip_runtime.h>
#include <hip/hip_bf16.h>

typedef __attribute__((ext_vector_type(8))) short bf16x8;
typedef __attribute__((ext_vector_type(4))) float f32x4;

#define MFMA16(A, B, C) __builtin_amdgcn_mfma_f32_16x16x32_bf16(A, B, C, 0, 0, 0)

__device__ __forceinline__ unsigned short f2bf(float f) {
    unsigned int u = __float_as_uint(f);
    u += 0x7fffu + ((u >> 16) & 1u);
    return (unsigned short)(u >> 16);
}
__device__ __forceinline__ float bf2f(unsigned short h) {
    return __uint_as_float(((unsigned int)h) << 16);
}
__device__ __forceinline__ unsigned int pack_bf2(float lo, float hi) {
    __hip_bfloat162 h = __float22bfloat162_rn(make_float2(lo, hi)); // v_cvt_pk_bf16_f32
    return *reinterpret_cast<unsigned int*>(&h);
}

__device__ __forceinline__ void gload_lds16(const void* g, void* l) {
    __builtin_amdgcn_global_load_lds(
        (__attribute__((address_space(1))) unsigned int*)g,
        (__attribute__((address_space(3))) unsigned int*)l, 16, 0, 0);
}

// ---------------------------------------------------------------- converts
__global__ void cvt_kernel(const float* __restrict__ in, unsigned short* __restrict__ out, int n4) {
    const int i = blockIdx.x * 256 + threadIdx.x;
    if (i >= n4) return;
    const float4 v = ((const float4*)in)[i];
    uint2 o;
    o.x = pack_bf2(v.x, v.y);
    o.y = pack_bf2(v.z, v.w);
    ((uint2*)out)[i] = o;
}

// ---------------------------------------------------------------- doc starts
__global__ void docstart_kernel(const int* __restrict__ sid, int* __restrict__ ds) {
    const int i = blockIdx.x * 256 + threadIdx.x; // 0..4095
    const int b = i >> 11, s = i & 2047;
    const int* row = sid + b * 2048;
    const int v = row[s];
    int lo = 0, hi = s;
    while (lo < hi) { const int mid = (lo + hi) >> 1; if (row[mid] < v) lo = mid + 1; else hi = mid; }
    ds[i] = lo;
}

// ---------------------------------------------------------------- bt-GEMM (m97 structure + XCD swizzle)
template <int EPI>
__global__ __launch_bounds__(256) void gemm_bt(
    const unsigned short* __restrict__ A,
    const unsigned short* __restrict__ B,
    int K, int N,
    unsigned short* __restrict__ oq,
    unsigned short* __restrict__ ok,
    unsigned short* __restrict__ ov,
    float* __restrict__ of)
{
    __shared__ __align__(16) unsigned short sA[128 * 32];
    __shared__ __align__(16) unsigned short sB[128 * 32];
    const int tid = threadIdx.x;
    const int lane = tid & 63, wave = tid >> 6;
    const int wr = wave >> 1, wc = wave & 1;
    const int lr = lane & 15, lc = lane >> 4;

    // bijective XCD swizzle (grid.x*grid.y % 8 == 0 for both call sites)
    int bid = blockIdx.y * gridDim.x + blockIdx.x;
    const int cpx = (gridDim.x * gridDim.y) >> 3;
    bid = (bid & 7) * cpx + (bid >> 3);
    const int m0 = (bid / gridDim.x) * 128, n0 = (bid % gridDim.x) * 128;

    f32x4 acc[4][4];
#pragma unroll
    for (int i = 0; i < 4; i++)
#pragma unroll
        for (int j = 0; j < 4; j++) acc[i][j] = (f32x4){0.f, 0.f, 0.f, 0.f};

    const int u0 = tid, u1 = tid + 256;
    for (int k0 = 0; k0 < K; k0 += 32) {
        __syncthreads();
        gload_lds16(A + (size_t)(m0 + (u0 >> 2)) * K + k0 + (u0 & 3) * 8, &sA[u0 * 8]);
        gload_lds16(A + (size_t)(m0 + (u1 >> 2)) * K + k0 + (u1 & 3) * 8, &sA[u1 * 8]);
        gload_lds16(B + (size_t)(n0 + (u0 >> 2)) * K + k0 + (u0 & 3) * 8, &sB[u0 * 8]);
        gload_lds16(B + (size_t)(n0 + (u1 >> 2)) * K + k0 + (u1 & 3) * 8, &sB[u1 * 8]);
        __syncthreads();
        bf16x8 af[4], bfv[4];
#pragma unroll
        for (int i = 0; i < 4; i++) {
            af[i]  = *(const bf16x8*)&sA[(wr * 64 + i * 16 + lr) * 32 + lc * 8];
            bfv[i] = *(const bf16x8*)&sB[(wc * 64 + i * 16 + lr) * 32 + lc * 8];
        }
#pragma unroll
        for (int i = 0; i < 4; i++)
#pragma unroll
            for (int j = 0; j < 4; j++) acc[i][j] = MFMA16(af[i], bfv[j], acc[i][j]);
    }

    if (EPI == 0) {
#pragma unroll
        for (int i = 0; i < 4; i++) {
#pragma unroll
            for (int j = 0; j < 4; j++) {
                const int n = n0 + wc * 64 + j * 16 + lr;
                const int d = n & 63;
#pragma unroll
                for (int r = 0; r < 4; r++) {
                    const int m = m0 + wr * 64 + i * 16 + lc * 4 + r;
                    const int bb = m >> 11, s = m & 2047;
                    const unsigned short val = f2bf(acc[i][j][r]);
                    if (n < 2048) {
                        const int hh = n >> 6;
                        oq[((((size_t)bb * 32 + hh) * 2048 + s) << 6) + d] = val;
                    } else if (n < 2560) {
                        const int hh = (n >> 6) - 32;
                        ok[((((size_t)bb * 8 + hh) * 2048 + s) << 6) + d] = val;
                    } else {
                        const int hh = (n >> 6) - 40;
                        ov[((((size_t)bb * 8 + hh) * 2048 + s) << 6) + d] = val;
                    }
                }
            }
        }
    } else {
#pragma unroll
        for (int i = 0; i < 4; i++)
#pragma unroll
            for (int j = 0; j < 4; j++)
#pragma unroll
                for (int r = 0; r < 4; r++) {
                    const int m = m0 + wr * 64 + i * 16 + lc * 4 + r;
                    const int n = n0 + wc * 64 + j * 16 + lr;
                    of[(size_t)m * N + n] = acc[i][j][r];
                }
    }
}

// ---------------------------------------------------------------- RoPE (in-place on Q and K, bf16)
__global__ void rope_kernel(unsigned short* __restrict__ Qb,
                            unsigned short* __restrict__ Kb,
                            const float* __restrict__ fc)
{
    const int NQ = 2 * 32 * 2048 * 32;
    int i = blockIdx.x * 256 + threadIdx.x;
    unsigned short* base;
    if (i < NQ) base = Qb;
    else { base = Kb; i -= NQ; }
    const int p = i & 31, s = (i >> 5) & 2047, bh = i >> 16;
    const size_t off = (((size_t)bh * 2048 + s) << 6) + p * 2;
    const unsigned int w = *(const unsigned int*)&base[off];
    const float t0 = bf2f((unsigned short)(w & 0xffffu));
    const float t1 = bf2f((unsigned short)(w >> 16));
    const float c = fc[(s * 32 + p) * 2], sn = fc[(s * 32 + p) * 2 + 1];
    *(unsigned int*)&base[off] = pack_bf2(t0 * c - t1 * sn, t0 * sn + t1 * c);
}

// ---------------------------------------------------------------- flash attention v3
// grid: (qtile 32 reversed, head 32, batch 2); block 256 = 4 waves; wave owns 16 q-rows.
// Swapped QK^T (C[k][q], q = lane&15) -> in-lane softmax. P redistribution into PV
// B-frags (FIXED): lane S holds pk[kk][h] = P[q=S&15][kv = kk*16 + (S>>4)*4 + 2h];
// dest lane T needs kv = B*32 + (T>>4)*8 + 2w  =>  kk = (lc>>1)+2B (DEST-dependent!),
// lc_S = 2*(lc&1) + (w>>1), h = w&1.  One shuffle can't carry two kk's from the same
// source lane, so shuffle BOTH kk candidates and v_cndmask by dest's lc>>1.
__global__ __launch_bounds__(256) void attn_kernel(
    const unsigned short* __restrict__ Q,
    const unsigned short* __restrict__ K,
    const unsigned short* __restrict__ V,
    const int* __restrict__ dstart,
    unsigned short* __restrict__ AO)
{
    const int qt = 31 - blockIdx.x; // heavy blocks first
    const int h = blockIdx.y, b = blockIdx.z;
    const int kvh = h >> 2;
    const int tid = threadIdx.x, lane = tid & 63, wave = tid >> 6;
    const int lr = lane & 15, lc = lane >> 4;
    const int q0 = qt * 64;
    const int qw = q0 + wave * 16;

    __shared__ __align__(16) unsigned short sK[64 * 64];   // chunk-XOR swizzled
    __shared__ __align__(16) unsigned short sVt[64][72];   // V^T, conflict-free writes

    const unsigned short* Qh = Q + (((size_t)b * 32 + h) * 2048) * 64;
    const unsigned short* Kh = K + (((size_t)b * 8 + kvh) * 2048) * 64;
    const unsigned short* Vh = V + (((size_t)b * 8 + kvh) * 2048) * 64;

    // Q B-frag: lane holds Q[qw+lr][lc*8 + j]
    const bf16x8 qf0 = *(const bf16x8*)&Qh[(size_t)(qw + lr) * 64 + lc * 8];
    const bf16x8 qf1 = *(const bf16x8*)&Qh[(size_t)(qw + lr) * 64 + 32 + lc * 8];

    const int qglob = qw + lr;
    const int dsl = dstart[b * 2048 + qglob];
    const int ds_wmin = dstart[b * 2048 + qw];
    const int t0 = dstart[b * 2048 + q0] & ~63;

    float mrow = -1e30f, lrow = 0.f;
    f32x4 oacc[4];
#pragma unroll
    for (int j = 0; j < 4; j++) oacc[j] = (f32x4){0.f, 0.f, 0.f, 0.f};

    for (int t = t0; t < q0 + 64; t += 64) {
        __syncthreads();
        // --- K stage: global_load_lds w16, source chunk-XOR pre-swizzled (m173)
        {
            int slot = tid;
            int r = slot >> 3, c = slot & 7;
            gload_lds16(Kh + (size_t)(t + r) * 64 + ((c ^ (r & 7)) * 8), &sK[slot * 8]);
            slot = tid + 256; r = slot >> 3; c = slot & 7;
            gload_lds16(Kh + (size_t)(t + r) * 64 + ((c ^ (r & 7)) * 8), &sK[slot * 8]);
        }
        // --- V stage transposed: wave w writes d-chunks w*8 and 32+w*8 for all 64 k-rows.
        // bank = 4e + lane/2 -> 32 banks x 2 lanes = conflict-free.
        {
            const int w8 = wave * 8;
            const uint4 va = *(const uint4*)&Vh[(size_t)(t + lane) * 64 + w8];
            const uint4 vb = *(const uint4*)&Vh[(size_t)(t + lane) * 64 + 32 + w8];
            const unsigned short* pa = (const unsigned short*)&va;
            const unsigned short* pb = (const unsigned short*)&vb;
#pragma unroll
            for (int e = 0; e < 8; e++) sVt[w8 + e][lane] = pa[e];
#pragma unroll
            for (int e = 0; e < 8; e++) sVt[32 + w8 + e][lane] = pb[e];
        }
        asm volatile("s_waitcnt vmcnt(0)" ::: "memory");
        __syncthreads();
        if (t > qw + 15 || t + 63 < ds_wmin) continue;

        // --- QK^T swapped: C[k][q], k = kk*16 + lc*4 + r, q = qw + lr
        f32x4 sc[4];
#pragma unroll
        for (int kk = 0; kk < 4; kk++) {
            const int krow = kk * 16 + lr;
            const bf16x8 kf0 = *(const bf16x8*)&sK[krow * 64 + ((lc ^ (lr & 7)) * 8)];
            const bf16x8 kf1 = *(const bf16x8*)&sK[krow * 64 + (((4 + lc) ^ (lr & 7)) * 8)];
            f32x4 a = (f32x4){0.f, 0.f, 0.f, 0.f};
            a = MFMA16(kf0, qf0, a);
            a = MFMA16(kf1, qf1, a);
            sc[kk] = a;
        }
        // --- mask + scale + in-lane softmax
        float vmax = -3e38f;
#pragma unroll
        for (int kk = 0; kk < 4; kk++)
#pragma unroll
            for (int r = 0; r < 4; r++) {
                const int kpos = t + kk * 16 + lc * 4 + r;
                const bool okm = (kpos <= qglob) && (kpos >= dsl);
                sc[kk][r] = okm ? sc[kk][r] * 0.125f : -3e38f;
                vmax = fmaxf(vmax, sc[kk][r]);
            }
        vmax = fmaxf(vmax, __shfl_xor(vmax, 16));
        vmax = fmaxf(vmax, __shfl_xor(vmax, 32));
        const float mnew = fmaxf(mrow, vmax);
        const float corr = __expf(mrow - mnew);
        mrow = mnew;

        float rsum = 0.f;
        unsigned int pk[4][2];
#pragma unroll
        for (int kk = 0; kk < 4; kk++) {
            const float p0 = __expf(sc[kk][0] - mnew);
            const float p1 = __expf(sc[kk][1] - mnew);
            const float p2 = __expf(sc[kk][2] - mnew);
            const float p3 = __expf(sc[kk][3] - mnew);
            rsum += (p0 + p1) + (p2 + p3);
            pk[kk][0] = pack_bf2(p0, p1);
            pk[kk][1] = pack_bf2(p2, p3);
        }
        rsum += __shfl_xor(rsum, 16);
        rsum += __shfl_xor(rsum, 32);
        lrow = lrow * corr + rsum;
#pragma unroll
        for (int j = 0; j < 4; j++)
#pragma unroll
            for (int r = 0; r < 4; r++) oacc[j][r] *= corr;

        // --- redistribute P -> PV B-frags (derivation in header comment)
        const int srcEven = 32 * (lc & 1) + lr;   // lc_S = 2*(lc&1),   for w = 0,1
        const int srcOdd  = srcEven + 16;         // lc_S = 2*(lc&1)+1, for w = 2,3
        const bool hiKK = (lc & 2) != 0;          // dest's kk selector (lc>>1)
        union { unsigned int w[4]; bf16x8 v; } B0, B1;
        {
            unsigned int a, c;
            a = __shfl(pk[0][0], srcEven); c = __shfl(pk[1][0], srcEven); B0.w[0] = hiKK ? c : a;
            a = __shfl(pk[0][1], srcEven); c = __shfl(pk[1][1], srcEven); B0.w[1] = hiKK ? c : a;
            a = __shfl(pk[0][0], srcOdd);  c = __shfl(pk[1][0], srcOdd);  B0.w[2] = hiKK ? c : a;
            a = __shfl(pk[0][1], srcOdd);  c = __shfl(pk[1][1], srcOdd);  B0.w[3] = hiKK ? c : a;
            a = __shfl(pk[2][0], srcEven); c = __shfl(pk[3][0], srcEven); B1.w[0] = hiKK ? c : a;
            a = __shfl(pk[2][1], srcEven); c = __shfl(pk[3][1], srcEven); B1.w[1] = hiKK ? c : a;
            a = __shfl(pk[2][0], srcOdd);  c = __shfl(pk[3][0], srcOdd);  B1.w[2] = hiKK ? c : a;
            a = __shfl(pk[2][1], srcOdd);  c = __shfl(pk[3][1], srcOdd);  B1.w[3] = hiKK ? c : a;
        }

        // --- PV: O^T = V^T x P^T, C[d][q]: d = j*16 + lc*4 + r, q = qw + lr
#pragma unroll
        for (int j = 0; j < 4; j++) {
            const bf16x8 a0 = *(const bf16x8*)&sVt[j * 16 + lr][lc * 8];
            const bf16x8 a1 = *(const bf16x8*)&sVt[j * 16 + lr][32 + lc * 8];
            oacc[j] = MFMA16(a0, B0.v, oacc[j]);
            oacc[j] = MFMA16(a1, B1.v, oacc[j]);
        }
    }

    // --- epilogue: transpose via LDS (reuse sVt rows per wave), coalesced stores
    __syncthreads();
    const float inv = 1.0f / lrow;
#pragma unroll
    for (int j = 0; j < 4; j++)
#pragma unroll
        for (int p = 0; p < 2; p++) {
            const unsigned int w = pack_bf2(oacc[j][2 * p] * inv, oacc[j][2 * p + 1] * inv);
            *(unsigned int*)&sVt[wave * 16 + lr][j * 16 + lc * 4 + 2 * p] = w;
        }
    __syncthreads();
#pragma unroll
    for (int half = 0; half < 2; half++) {
        const int c = lane + 64 * half;
        const int row = c >> 3, ch = c & 7;
        const uint4 o = *(const uint4*)&sVt[wave * 16 + row][ch * 8];
        *(uint4*)&AO[((size_t)b * 2048 + qw + row) * 2048 + h * 64 + ch * 8] = o;
    }
}

// ---------------------------------------------------------------- host
extern "C" void kernel_launch(void* const* d_in, const int* in_sizes, int n_in,
                              void* d_out, int out_size, void* d_ws, size_t ws_size,
                              hipStream_t stream) {
    const float* x  = (const float*)d_in[0];
    const float* fc = (const float*)d_in[1];
    const int* sid  = (const int*)d_in[2];
    const float* wq = (const float*)d_in[3];
    const float* wk = (const float*)d_in[4];
    const float* wv = (const float*)d_in[5];
    const float* wo = (const float*)d_in[6];
    float* out = (float*)d_out;

    unsigned short* xb   = (unsigned short*)d_ws;
    unsigned short* wqkv = xb + (size_t)4096 * 2048;
    unsigned short* wob  = wqkv + (size_t)3072 * 2048;
    unsigned short* Qb   = wob + (size_t)2048 * 2048;
    unsigned short* Kb   = Qb + (size_t)2 * 32 * 2048 * 64;
    unsigned short* Vb   = Kb + (size_t)2 * 8 * 2048 * 64;
    unsigned short* AO   = Vb + (size_t)2 * 8 * 2048 * 64;
    int* dstart = (int*)(AO + (size_t)4096 * 2048);

    cvt_kernel<<<8192, 256, 0, stream>>>(x, xb, 2097152);
    cvt_kernel<<<4096, 256, 0, stream>>>(wq, wqkv, 1048576);
    cvt_kernel<<<1024, 256, 0, stream>>>(wk, wqkv + (size_t)2048 * 2048, 262144);
    cvt_kernel<<<1024, 256, 0, stream>>>(wv, wqkv + (size_t)2560 * 2048, 262144);
    cvt_kernel<<<4096, 256, 0, stream>>>(wo, wob, 1048576);
    docstart_kernel<<<16, 256, 0, stream>>>(sid, dstart);
    gemm_bt<0><<<dim3(24, 32), 256, 0, stream>>>(xb, wqkv, 2048, 3072, Qb, Kb, Vb, nullptr);
    rope_kernel<<<20480, 256, 0, stream>>>(Qb, Kb, fc);
    attn_kernel<<<dim3(32, 32, 2), 256, 0, stream>>>(Qb, Kb, Vb, dstart, AO);
    gemm_bt<1><<<dim3(16, 32), 256, 0, stream>>>(AO, wob, 2048, 2048, nullptr, nullptr, nullptr, out);
}

// Round 5
// 218.313 us; speedup vs baseline: 1.1676x; 1.0126x over previous
//
#include <hip/hip_runtime.h>
#include <hip/hip_bf16.h>

typedef __attribute__((ext_vector_type(8))) short bf16x8;
typedef __attribute__((ext_vector_type(4))) float f32x4;

#define MFMA16(A, B, C) __builtin_amdgcn_mfma_f32_16x16x32_bf16(A, B, C, 0, 0, 0)

__device__ __forceinline__ unsigned short f2bf(float f) {
    unsigned int u = __float_as_uint(f);
    u += 0x7fffu + ((u >> 16) & 1u);
    return (unsigned short)(u >> 16);
}
__device__ __forceinline__ float bf2f(unsigned short h) {
    return __uint_as_float(((unsigned int)h) << 16);
}
__device__ __forceinline__ unsigned int pack_bf2(float lo, float hi) {
    __hip_bfloat162 h = __float22bfloat162_rn(make_float2(lo, hi)); // v_cvt_pk_bf16_f32
    return *reinterpret_cast<unsigned int*>(&h);
}

__device__ __forceinline__ void gload_lds16(const void* g, void* l) {
    __builtin_amdgcn_global_load_lds(
        (__attribute__((address_space(1))) unsigned int*)g,
        (__attribute__((address_space(3))) unsigned int*)l, 16, 0, 0);
}

// ---------------------------------------------------------------- converts
__global__ void cvt_kernel(const float* __restrict__ in, unsigned short* __restrict__ out, int n4) {
    const int i = blockIdx.x * 256 + threadIdx.x;
    if (i >= n4) return;
    const float4 v = ((const float4*)in)[i];
    uint2 o;
    o.x = pack_bf2(v.x, v.y);
    o.y = pack_bf2(v.z, v.w);
    ((uint2*)out)[i] = o;
}

// ---------------------------------------------------------------- doc starts
__global__ void docstart_kernel(const int* __restrict__ sid, int* __restrict__ ds) {
    const int i = blockIdx.x * 256 + threadIdx.x; // 0..4095
    const int b = i >> 11, s = i & 2047;
    const int* row = sid + b * 2048;
    const int v = row[s];
    int lo = 0, hi = s;
    while (lo < hi) { const int mid = (lo + hi) >> 1; if (row[mid] < v) lo = mid + 1; else hi = mid; }
    ds[i] = lo;
}

// ---------------------------------------------------------------- QKV 256x256 8-phase GEMM
// C[m][n] = sum_k A[m][k]*B[n][k]; A:(4096,2048), B:(3072,2048) bf16 row-major.
// 512 thr = 8 waves (2M x 4N); per-wave out 128x64 via quadrants (mh,nh);
// LDS 128 KiB = [buf2][op2][half2][128x64]; st_16x32 swizzle; counted vmcnt(6).
#define QKV_K 2048
#define QKV_NT 32
__global__ __launch_bounds__(512, 2) void gemm_qkv8(
    const unsigned short* __restrict__ A,
    const unsigned short* __restrict__ B,
    unsigned short* __restrict__ oq,
    unsigned short* __restrict__ ok,
    unsigned short* __restrict__ ov)
{
    __shared__ __align__(16) unsigned short S[2][2][2][8192]; // 128 KiB
    const int tid = threadIdx.x, lane = tid & 63, w = tid >> 6;
    const int wr = w >> 2, wc = w & 3;
    const int lr = lane & 15, lc = lane >> 4;

    // XCD swizzle over 192 blocks (192 % 8 == 0)
    int bid = blockIdx.x;
    bid = (bid & 7) * 24 + (bid >> 3);
    const int m0 = (bid / 12) * 256, n0 = (bid % 12) * 256;

    // per-thread stage geometry: LDS byte offsets o0/o1; inverse-swizzled (row,col)
    const int o0 = (w << 11) + (lane << 4);
    const int o1 = o0 + 1024;
    const int v0 = o0 ^ (((o0 >> 9) & 1) << 5);
    const int v1 = o1 ^ (((o1 >> 9) & 1) << 5);
    const int r0 = v0 >> 7, c0 = (v0 & 127) >> 1;
    const int r1 = v1 >> 7, c1 = (v1 & 127) >> 1;
    const size_t aoff0 = (size_t)(m0 + r0) * QKV_K + c0;
    const size_t aoff1 = (size_t)(m0 + r1) * QKV_K + c1;
    const size_t boff0 = (size_t)(n0 + r0) * QKV_K + c0;
    const size_t boff1 = (size_t)(n0 + r1) * QKV_K + c1;
    const int d0 = o0 >> 1, d1 = o1 >> 1;

    f32x4 acc[2][2][4][2];
#pragma unroll
    for (int a = 0; a < 2; a++)
#pragma unroll
        for (int bq = 0; bq < 2; bq++)
#pragma unroll
            for (int i = 0; i < 4; i++)
#pragma unroll
                for (int j = 0; j < 2; j++) acc[a][bq][i][j] = (f32x4){0.f, 0.f, 0.f, 0.f};

    bf16x8 Af[4][2], Bf0[2][2], Bf1[2][2];

    auto STAGE_A = [&](int bf, int h, int kt) {
        gload_lds16(A + aoff0 + (size_t)h * 128 * QKV_K + (size_t)kt * 64, &S[bf][0][h][d0]);
        gload_lds16(A + aoff1 + (size_t)h * 128 * QKV_K + (size_t)kt * 64, &S[bf][0][h][d1]);
    };
    auto STAGE_B = [&](int bf, int h, int kt) {
        gload_lds16(B + boff0 + (size_t)h * 128 * QKV_K + (size_t)kt * 64, &S[bf][1][h][d0]);
        gload_lds16(B + boff1 + (size_t)h * 128 * QKV_K + (size_t)kt * 64, &S[bf][1][h][d1]);
    };
    auto LDA = [&](int bf, int mh) {
#pragma unroll
        for (int i = 0; i < 4; i++)
#pragma unroll
            for (int kh = 0; kh < 2; kh++) {
                int by = ((wr * 64 + i * 16 + lr) << 7) + (kh << 6) + (lc << 4);
                by ^= ((by >> 9) & 1) << 5;
                Af[i][kh] = *(const bf16x8*)((const char*)&S[bf][0][mh][0] + by);
            }
    };
    auto LDB = [&](int bf, int nh, bf16x8 (&Bf)[2][2]) {
#pragma unroll
        for (int j = 0; j < 2; j++)
#pragma unroll
            for (int kh = 0; kh < 2; kh++) {
                int by = ((wc * 32 + j * 16 + lr) << 7) + (kh << 6) + (lc << 4);
                by ^= ((by >> 9) & 1) << 5;
                Bf[j][kh] = *(const bf16x8*)((const char*)&S[bf][1][nh][0] + by);
            }
    };
    auto QUAD = [&](f32x4 (&ac)[4][2], bf16x8 (&Bf)[2][2]) {
        __builtin_amdgcn_s_setprio(1);
#pragma unroll
        for (int i = 0; i < 4; i++)
#pragma unroll
            for (int j = 0; j < 2; j++)
#pragma unroll
                for (int kh = 0; kh < 2; kh++)
                    ac[i][j] = MFMA16(Af[i][kh], Bf[j][kh], ac[i][j]);
        __builtin_amdgcn_s_setprio(0);
    };

#define BAR() __builtin_amdgcn_s_barrier()
#define LGKM0() asm volatile("s_waitcnt lgkmcnt(0)" ::: "memory")

    // ---- prologue: tile0 (A0,A1,B0,B1)->buf0; A0[1],B1[1],A1[1]->buf1; drain to 3
    STAGE_A(0, 0, 0); STAGE_A(0, 1, 0); STAGE_B(0, 0, 0); STAGE_B(0, 1, 0);
    STAGE_A(1, 0, 1); STAGE_B(1, 1, 1); STAGE_A(1, 1, 1);
    asm volatile("s_waitcnt vmcnt(6)" ::: "memory");
    BAR();

    auto GROUP = [&](int g, int bf) {
        // ---- ph1: quadrant (0,0): read A0-chunk + B0-chunk; stage B0[g+1] -> other buf
        LDA(bf, 0); LDB(bf, 0, Bf0);
        if (g + 1 < QKV_NT) STAGE_B(bf ^ 1, 0, g + 1);
        BAR(); LGKM0();
        QUAD(acc[0][0], Bf0);
        BAR();
        // ---- ph2: (0,1): read B1-chunk (A kept); stage A0[g+2] -> current buf
        LDB(bf, 1, Bf1);
        if (g + 2 < QKV_NT) STAGE_A(bf, 0, g + 2);
        BAR(); LGKM0();
        QUAD(acc[0][1], Bf1);
        BAR();
        // ---- ph3: (1,1): read A1-chunk (B1 kept); stage B1[g+2] -> current buf
        LDA(bf, 1);
        if (g + 2 < QKV_NT) STAGE_B(bf, 1, g + 2);
        BAR(); LGKM0();
        QUAD(acc[1][1], Bf1);
        BAR();
        // ---- ph4: (1,0): no reads (A1,B0 kept); stage A1[g+2] -> current buf
        if (g + 2 < QKV_NT) STAGE_A(bf, 1, g + 2);
        BAR();
        QUAD(acc[1][0], Bf0);
        if (g == QKV_NT - 2) { asm volatile("s_waitcnt vmcnt(0)" ::: "memory"); }
        else                 { asm volatile("s_waitcnt vmcnt(6)" ::: "memory"); }
        BAR();
    };

#pragma unroll 1
    for (int g = 0; g < QKV_NT; g += 2) {
        GROUP(g, 0);
        GROUP(g + 1, 1);
    }

    // ---- epilogue: scatter into Q:(B,32,S,64), K/V:(B,8,S,64) bf16
#pragma unroll
    for (int mh = 0; mh < 2; mh++)
#pragma unroll
        for (int nh = 0; nh < 2; nh++)
#pragma unroll
            for (int i = 0; i < 4; i++)
#pragma unroll
                for (int j = 0; j < 2; j++) {
                    const int n = n0 + nh * 128 + wc * 32 + j * 16 + lr;
                    const int d = n & 63;
                    const int hh6 = n >> 6;
#pragma unroll
                    for (int r = 0; r < 4; r++) {
                        const int m = m0 + mh * 128 + wr * 64 + i * 16 + lc * 4 + r;
                        const int bb = m >> 11, s = m & 2047;
                        const unsigned short val = f2bf(acc[mh][nh][i][j][r]);
                        if (n < 2048) {
                            oq[((((size_t)bb * 32 + hh6) * 2048 + s) << 6) + d] = val;
                        } else if (n < 2560) {
                            ok[((((size_t)bb * 8 + (hh6 - 32)) * 2048 + s) << 6) + d] = val;
                        } else {
                            ov[((((size_t)bb * 8 + (hh6 - 40)) * 2048 + s) << 6) + d] = val;
                        }
                    }
                }
}
#undef BAR
#undef LGKM0

// ---------------------------------------------------------------- bt-GEMM (m97 structure + XCD swizzle) for out-proj
template <int EPI>
__global__ __launch_bounds__(256) void gemm_bt(
    const unsigned short* __restrict__ A,
    const unsigned short* __restrict__ B,
    int K, int N,
    unsigned short* __restrict__ oq,
    unsigned short* __restrict__ ok,
    unsigned short* __restrict__ ov,
    float* __restrict__ of)
{
    __shared__ __align__(16) unsigned short sA[128 * 32];
    __shared__ __align__(16) unsigned short sB[128 * 32];
    const int tid = threadIdx.x;
    const int lane = tid & 63, wave = tid >> 6;
    const int wr = wave >> 1, wc = wave & 1;
    const int lr = lane & 15, lc = lane >> 4;

    int bid = blockIdx.y * gridDim.x + blockIdx.x;
    const int cpx = (gridDim.x * gridDim.y) >> 3;
    bid = (bid & 7) * cpx + (bid >> 3);
    const int m0 = (bid / gridDim.x) * 128, n0 = (bid % gridDim.x) * 128;

    f32x4 acc[4][4];
#pragma unroll
    for (int i = 0; i < 4; i++)
#pragma unroll
        for (int j = 0; j < 4; j++) acc[i][j] = (f32x4){0.f, 0.f, 0.f, 0.f};

    const int u0 = tid, u1 = tid + 256;
    for (int k0 = 0; k0 < K; k0 += 32) {
        __syncthreads();
        gload_lds16(A + (size_t)(m0 + (u0 >> 2)) * K + k0 + (u0 & 3) * 8, &sA[u0 * 8]);
        gload_lds16(A + (size_t)(m0 + (u1 >> 2)) * K + k0 + (u1 & 3) * 8, &sA[u1 * 8]);
        gload_lds16(B + (size_t)(n0 + (u0 >> 2)) * K + k0 + (u0 & 3) * 8, &sB[u0 * 8]);
        gload_lds16(B + (size_t)(n0 + (u1 >> 2)) * K + k0 + (u1 & 3) * 8, &sB[u1 * 8]);
        __syncthreads();
        bf16x8 af[4], bfv[4];
#pragma unroll
        for (int i = 0; i < 4; i++) {
            af[i]  = *(const bf16x8*)&sA[(wr * 64 + i * 16 + lr) * 32 + lc * 8];
            bfv[i] = *(const bf16x8*)&sB[(wc * 64 + i * 16 + lr) * 32 + lc * 8];
        }
#pragma unroll
        for (int i = 0; i < 4; i++)
#pragma unroll
            for (int j = 0; j < 4; j++) acc[i][j] = MFMA16(af[i], bfv[j], acc[i][j]);
    }

    if (EPI == 0) {
#pragma unroll
        for (int i = 0; i < 4; i++) {
#pragma unroll
            for (int j = 0; j < 4; j++) {
                const int n = n0 + wc * 64 + j * 16 + lr;
                const int d = n & 63;
#pragma unroll
                for (int r = 0; r < 4; r++) {
                    const int m = m0 + wr * 64 + i * 16 + lc * 4 + r;
                    const int bb = m >> 11, s = m & 2047;
                    const unsigned short val = f2bf(acc[i][j][r]);
                    if (n < 2048) {
                        const int hh = n >> 6;
                        oq[((((size_t)bb * 32 + hh) * 2048 + s) << 6) + d] = val;
                    } else if (n < 2560) {
                        const int hh = (n >> 6) - 32;
                        ok[((((size_t)bb * 8 + hh) * 2048 + s) << 6) + d] = val;
                    } else {
                        const int hh = (n >> 6) - 40;
                        ov[((((size_t)bb * 8 + hh) * 2048 + s) << 6) + d] = val;
                    }
                }
            }
        }
    } else {
#pragma unroll
        for (int i = 0; i < 4; i++)
#pragma unroll
            for (int j = 0; j < 4; j++)
#pragma unroll
                for (int r = 0; r < 4; r++) {
                    const int m = m0 + wr * 64 + i * 16 + lc * 4 + r;
                    const int n = n0 + wc * 64 + j * 16 + lr;
                    of[(size_t)m * N + n] = acc[i][j][r];
                }
    }
}

// ---------------------------------------------------------------- RoPE (in-place on Q and K, bf16)
__global__ void rope_kernel(unsigned short* __restrict__ Qb,
                            unsigned short* __restrict__ Kb,
                            const float* __restrict__ fc)
{
    const int NQ = 2 * 32 * 2048 * 32;
    int i = blockIdx.x * 256 + threadIdx.x;
    unsigned short* base;
    if (i < NQ) base = Qb;
    else { base = Kb; i -= NQ; }
    const int p = i & 31, s = (i >> 5) & 2047, bh = i >> 16;
    const size_t off = (((size_t)bh * 2048 + s) << 6) + p * 2;
    const unsigned int w = *(const unsigned int*)&base[off];
    const float t0 = bf2f((unsigned short)(w & 0xffffu));
    const float t1 = bf2f((unsigned short)(w >> 16));
    const float c = fc[(s * 32 + p) * 2], sn = fc[(s * 32 + p) * 2 + 1];
    *(unsigned int*)&base[off] = pack_bf2(t0 * c - t1 * sn, t0 * sn + t1 * c);
}

// ---------------------------------------------------------------- flash attention v3 (unchanged, verified)
__global__ __launch_bounds__(256) void attn_kernel(
    const unsigned short* __restrict__ Q,
    const unsigned short* __restrict__ K,
    const unsigned short* __restrict__ V,
    const int* __restrict__ dstart,
    unsigned short* __restrict__ AO)
{
    const int qt = 31 - blockIdx.x; // heavy blocks first
    const int h = blockIdx.y, b = blockIdx.z;
    const int kvh = h >> 2;
    const int tid = threadIdx.x, lane = tid & 63, wave = tid >> 6;
    const int lr = lane & 15, lc = lane >> 4;
    const int q0 = qt * 64;
    const int qw = q0 + wave * 16;

    __shared__ __align__(16) unsigned short sK[64 * 64];   // chunk-XOR swizzled
    __shared__ __align__(16) unsigned short sVt[64][72];   // V^T, conflict-free writes

    const unsigned short* Qh = Q + (((size_t)b * 32 + h) * 2048) * 64;
    const unsigned short* Kh = K + (((size_t)b * 8 + kvh) * 2048) * 64;
    const unsigned short* Vh = V + (((size_t)b * 8 + kvh) * 2048) * 64;

    const bf16x8 qf0 = *(const bf16x8*)&Qh[(size_t)(qw + lr) * 64 + lc * 8];
    const bf16x8 qf1 = *(const bf16x8*)&Qh[(size_t)(qw + lr) * 64 + 32 + lc * 8];

    const int qglob = qw + lr;
    const int dsl = dstart[b * 2048 + qglob];
    const int ds_wmin = dstart[b * 2048 + qw];
    const int t0 = dstart[b * 2048 + q0] & ~63;

    float mrow = -1e30f, lrow = 0.f;
    f32x4 oacc[4];
#pragma unroll
    for (int j = 0; j < 4; j++) oacc[j] = (f32x4){0.f, 0.f, 0.f, 0.f};

    for (int t = t0; t < q0 + 64; t += 64) {
        __syncthreads();
        {
            int slot = tid;
            int r = slot >> 3, c = slot & 7;
            gload_lds16(Kh + (size_t)(t + r) * 64 + ((c ^ (r & 7)) * 8), &sK[slot * 8]);
            slot = tid + 256; r = slot >> 3; c = slot & 7;
            gload_lds16(Kh + (size_t)(t + r) * 64 + ((c ^ (r & 7)) * 8), &sK[slot * 8]);
        }
        {
            const int w8 = wave * 8;
            const uint4 va = *(const uint4*)&Vh[(size_t)(t + lane) * 64 + w8];
            const uint4 vb = *(const uint4*)&Vh[(size_t)(t + lane) * 64 + 32 + w8];
            const unsigned short* pa = (const unsigned short*)&va;
            const unsigned short* pb = (const unsigned short*)&vb;
#pragma unroll
            for (int e = 0; e < 8; e++) sVt[w8 + e][lane] = pa[e];
#pragma unroll
            for (int e = 0; e < 8; e++) sVt[32 + w8 + e][lane] = pb[e];
        }
        asm volatile("s_waitcnt vmcnt(0)" ::: "memory");
        __syncthreads();
        if (t > qw + 15 || t + 63 < ds_wmin) continue;

        f32x4 sc[4];
#pragma unroll
        for (int kk = 0; kk < 4; kk++) {
            const int krow = kk * 16 + lr;
            const bf16x8 kf0 = *(const bf16x8*)&sK[krow * 64 + ((lc ^ (lr & 7)) * 8)];
            const bf16x8 kf1 = *(const bf16x8*)&sK[krow * 64 + (((4 + lc) ^ (lr & 7)) * 8)];
            f32x4 a = (f32x4){0.f, 0.f, 0.f, 0.f};
            a = MFMA16(kf0, qf0, a);
            a = MFMA16(kf1, qf1, a);
            sc[kk] = a;
        }
        float vmax = -3e38f;
#pragma unroll
        for (int kk = 0; kk < 4; kk++)
#pragma unroll
            for (int r = 0; r < 4; r++) {
                const int kpos = t + kk * 16 + lc * 4 + r;
                const bool okm = (kpos <= qglob) && (kpos >= dsl);
                sc[kk][r] = okm ? sc[kk][r] * 0.125f : -3e38f;
                vmax = fmaxf(vmax, sc[kk][r]);
            }
        vmax = fmaxf(vmax, __shfl_xor(vmax, 16));
        vmax = fmaxf(vmax, __shfl_xor(vmax, 32));
        const float mnew = fmaxf(mrow, vmax);
        const float corr = __expf(mrow - mnew);
        mrow = mnew;

        float rsum = 0.f;
        unsigned int pk[4][2];
#pragma unroll
        for (int kk = 0; kk < 4; kk++) {
            const float p0 = __expf(sc[kk][0] - mnew);
            const float p1 = __expf(sc[kk][1] - mnew);
            const float p2 = __expf(sc[kk][2] - mnew);
            const float p3 = __expf(sc[kk][3] - mnew);
            rsum += (p0 + p1) + (p2 + p3);
            pk[kk][0] = pack_bf2(p0, p1);
            pk[kk][1] = pack_bf2(p2, p3);
        }
        rsum += __shfl_xor(rsum, 16);
        rsum += __shfl_xor(rsum, 32);
        lrow = lrow * corr + rsum;
#pragma unroll
        for (int j = 0; j < 4; j++)
#pragma unroll
            for (int r = 0; r < 4; r++) oacc[j][r] *= corr;

        const int srcEven = 32 * (lc & 1) + lr;
        const int srcOdd  = srcEven + 16;
        const bool hiKK = (lc & 2) != 0;
        union { unsigned int w[4]; bf16x8 v; } B0, B1;
        {
            unsigned int a, c;
            a = __shfl(pk[0][0], srcEven); c = __shfl(pk[1][0], srcEven); B0.w[0] = hiKK ? c : a;
            a = __shfl(pk[0][1], srcEven); c = __shfl(pk[1][1], srcEven); B0.w[1] = hiKK ? c : a;
            a = __shfl(pk[0][0], srcOdd);  c = __shfl(pk[1][0], srcOdd);  B0.w[2] = hiKK ? c : a;
            a = __shfl(pk[0][1], srcOdd);  c = __shfl(pk[1][1], srcOdd);  B0.w[3] = hiKK ? c : a;
            a = __shfl(pk[2][0], srcEven); c = __shfl(pk[3][0], srcEven); B1.w[0] = hiKK ? c : a;
            a = __shfl(pk[2][1], srcEven); c = __shfl(pk[3][1], srcEven); B1.w[1] = hiKK ? c : a;
            a = __shfl(pk[2][0], srcOdd);  c = __shfl(pk[3][0], srcOdd);  B1.w[2] = hiKK ? c : a;
            a = __shfl(pk[2][1], srcOdd);  c = __shfl(pk[3][1], srcOdd);  B1.w[3] = hiKK ? c : a;
        }

#pragma unroll
        for (int j = 0; j < 4; j++) {
            const bf16x8 a0 = *(const bf16x8*)&sVt[j * 16 + lr][lc * 8];
            const bf16x8 a1 = *(const bf16x8*)&sVt[j * 16 + lr][32 + lc * 8];
            oacc[j] = MFMA16(a0, B0.v, oacc[j]);
            oacc[j] = MFMA16(a1, B1.v, oacc[j]);
        }
    }

    __syncthreads();
    const float inv = 1.0f / lrow;
#pragma unroll
    for (int j = 0; j < 4; j++)
#pragma unroll
        for (int p = 0; p < 2; p++) {
            const unsigned int w = pack_bf2(oacc[j][2 * p] * inv, oacc[j][2 * p + 1] * inv);
            *(unsigned int*)&sVt[wave * 16 + lr][j * 16 + lc * 4 + 2 * p] = w;
        }
    __syncthreads();
#pragma unroll
    for (int half = 0; half < 2; half++) {
        const int c = lane + 64 * half;
        const int row = c >> 3, ch = c & 7;
        const uint4 o = *(const uint4*)&sVt[wave * 16 + row][ch * 8];
        *(uint4*)&AO[((size_t)b * 2048 + qw + row) * 2048 + h * 64 + ch * 8] = o;
    }
}

// ---------------------------------------------------------------- host
extern "C" void kernel_launch(void* const* d_in, const int* in_sizes, int n_in,
                              void* d_out, int out_size, void* d_ws, size_t ws_size,
                              hipStream_t stream) {
    const float* x  = (const float*)d_in[0];
    const float* fc = (const float*)d_in[1];
    const int* sid  = (const int*)d_in[2];
    const float* wq = (const float*)d_in[3];
    const float* wk = (const float*)d_in[4];
    const float* wv = (const float*)d_in[5];
    const float* wo = (const float*)d_in[6];
    float* out = (float*)d_out;

    unsigned short* xb   = (unsigned short*)d_ws;
    unsigned short* wqkv = xb + (size_t)4096 * 2048;
    unsigned short* wob  = wqkv + (size_t)3072 * 2048;
    unsigned short* Qb   = wob + (size_t)2048 * 2048;
    unsigned short* Kb   = Qb + (size_t)2 * 32 * 2048 * 64;
    unsigned short* Vb   = Kb + (size_t)2 * 8 * 2048 * 64;
    unsigned short* AO   = Vb + (size_t)2 * 8 * 2048 * 64;
    int* dstart = (int*)(AO + (size_t)4096 * 2048);

    cvt_kernel<<<8192, 256, 0, stream>>>(x, xb, 2097152);
    cvt_kernel<<<4096, 256, 0, stream>>>(wq, wqkv, 1048576);
    cvt_kernel<<<1024, 256, 0, stream>>>(wk, wqkv + (size_t)2048 * 2048, 262144);
    cvt_kernel<<<1024, 256, 0, stream>>>(wv, wqkv + (size_t)2560 * 2048, 262144);
    cvt_kernel<<<4096, 256, 0, stream>>>(wo, wob, 1048576);
    docstart_kernel<<<16, 256, 0, stream>>>(sid, dstart);
    gemm_qkv8<<<dim3(192), 512, 0, stream>>>(xb, wqkv, Qb, Kb, Vb);
    rope_kernel<<<20480, 256, 0, stream>>>(Qb, Kb, fc);
    attn_kernel<<<dim3(32, 32, 2), 256, 0, stream>>>(Qb, Kb, Vb, dstart, AO);
    gemm_bt<1><<<dim3(16, 32), 256, 0, stream>>>(AO, wob, 2048, 2048, nullptr, nullptr, nullptr, out);
}

// Round 6
// 209.361 us; speedup vs baseline: 1.2175x; 1.0428x over previous
//
#include <hip/hip_runtime.h>
#include <hip/hip_bf16.h>

typedef __attribute__((ext_vector_type(8))) short bf16x8;
typedef __attribute__((ext_vector_type(4))) float f32x4;

#define MFMA16(A, B, C) __builtin_amdgcn_mfma_f32_16x16x32_bf16(A, B, C, 0, 0, 0)

__device__ __forceinline__ unsigned short f2bf(float f) {
    unsigned int u = __float_as_uint(f);
    u += 0x7fffu + ((u >> 16) & 1u);
    return (unsigned short)(u >> 16);
}
__device__ __forceinline__ float bf2f(unsigned short h) {
    return __uint_as_float(((unsigned int)h) << 16);
}
__device__ __forceinline__ unsigned int pack_bf2(float lo, float hi) {
    __hip_bfloat162 h = __float22bfloat162_rn(make_float2(lo, hi)); // v_cvt_pk_bf16_f32
    return *reinterpret_cast<unsigned int*>(&h);
}

__device__ __forceinline__ void gload_lds16(const void* g, void* l) {
    __builtin_amdgcn_global_load_lds(
        (__attribute__((address_space(1))) unsigned int*)g,
        (__attribute__((address_space(3))) unsigned int*)l, 16, 0, 0);
}

// LDS swizzle for [128 rows][64 bf16] regions (128 B/row): spread the 8 16B
// chunks of a row across banks by XOR with row&7 (involution; 16-row reads
// land 2 rows/chunk = 2-way = free per m136). Derivation: bank = colb>>2 & 31
// depends only on colb; rows alias -> 16-way without this.
__device__ __forceinline__ int swz128(int by) {
    return by ^ (((by >> 7) & 7) << 4);
}

// ---------------------------------------------------------------- converts
__global__ void cvt_kernel(const float* __restrict__ in, unsigned short* __restrict__ out, int n4) {
    const int i = blockIdx.x * 256 + threadIdx.x;
    if (i >= n4) return;
    const float4 v = ((const float4*)in)[i];
    uint2 o;
    o.x = pack_bf2(v.x, v.y);
    o.y = pack_bf2(v.z, v.w);
    ((uint2*)out)[i] = o;
}

// ---------------------------------------------------------------- doc starts
__global__ void docstart_kernel(const int* __restrict__ sid, int* __restrict__ ds) {
    const int i = blockIdx.x * 256 + threadIdx.x; // 0..4095
    const int b = i >> 11, s = i & 2047;
    const int* row = sid + b * 2048;
    const int v = row[s];
    int lo = 0, hi = s;
    while (lo < hi) { const int mid = (lo + hi) >> 1; if (row[mid] < v) lo = mid + 1; else hi = mid; }
    ds[i] = lo;
}

// ---------------------------------------------------------------- QKV 256x256 8-phase GEMM
// C[m][n] = sum_k A[m][k]*B[n][k]; A:(4096,2048), B:(3072,2048) bf16 row-major.
// 512 thr = 8 waves (2M x 4N); per-wave out 128x64 via quadrants (mh,nh);
// LDS 128 KiB = [buf2][op2][half2][128x64]; row&7 chunk-XOR swizzle; vmcnt(6).
#define QKV_K 2048
#define QKV_NT 32
__global__ __launch_bounds__(512, 2) void gemm_qkv8(
    const unsigned short* __restrict__ A,
    const unsigned short* __restrict__ B,
    unsigned short* __restrict__ oq,
    unsigned short* __restrict__ ok,
    unsigned short* __restrict__ ov)
{
    __shared__ __align__(16) unsigned short S[2][2][2][8192]; // 128 KiB
    const int tid = threadIdx.x, lane = tid & 63, w = tid >> 6;
    const int wr = w >> 2, wc = w & 3;
    const int lr = lane & 15, lc = lane >> 4;

    // XCD swizzle over 192 blocks (192 % 8 == 0)
    int bid = blockIdx.x;
    bid = (bid & 7) * 24 + (bid >> 3);
    const int m0 = (bid / 12) * 256, n0 = (bid % 12) * 256;

    // per-thread stage geometry: linear LDS byte offsets o0/o1 (gload_lds writes
    // linearly); global source is the INVERSE-swizzled (row,col) pair (rule #21).
    const int o0 = (w << 11) + (lane << 4);
    const int o1 = o0 + 1024;
    const int v0 = swz128(o0);
    const int v1 = swz128(o1);
    const int r0 = v0 >> 7, c0 = (v0 & 127) >> 1;
    const int r1 = v1 >> 7, c1 = (v1 & 127) >> 1;
    const size_t aoff0 = (size_t)(m0 + r0) * QKV_K + c0;
    const size_t aoff1 = (size_t)(m0 + r1) * QKV_K + c1;
    const size_t boff0 = (size_t)(n0 + r0) * QKV_K + c0;
    const size_t boff1 = (size_t)(n0 + r1) * QKV_K + c1;
    const int d0 = o0 >> 1, d1 = o1 >> 1;

    f32x4 acc[2][2][4][2];
#pragma unroll
    for (int a = 0; a < 2; a++)
#pragma unroll
        for (int bq = 0; bq < 2; bq++)
#pragma unroll
            for (int i = 0; i < 4; i++)
#pragma unroll
                for (int j = 0; j < 2; j++) acc[a][bq][i][j] = (f32x4){0.f, 0.f, 0.f, 0.f};

    bf16x8 Af[4][2], Bf0[2][2], Bf1[2][2];

    auto STAGE_A = [&](int bf, int h, int kt) {
        gload_lds16(A + aoff0 + (size_t)h * 128 * QKV_K + (size_t)kt * 64, &S[bf][0][h][d0]);
        gload_lds16(A + aoff1 + (size_t)h * 128 * QKV_K + (size_t)kt * 64, &S[bf][0][h][d1]);
    };
    auto STAGE_B = [&](int bf, int h, int kt) {
        gload_lds16(B + boff0 + (size_t)h * 128 * QKV_K + (size_t)kt * 64, &S[bf][1][h][d0]);
        gload_lds16(B + boff1 + (size_t)h * 128 * QKV_K + (size_t)kt * 64, &S[bf][1][h][d1]);
    };
    auto LDA = [&](int bf, int mh) {
#pragma unroll
        for (int i = 0; i < 4; i++)
#pragma unroll
            for (int kh = 0; kh < 2; kh++) {
                const int by = swz128(((wr * 64 + i * 16 + lr) << 7) + (kh << 6) + (lc << 4));
                Af[i][kh] = *(const bf16x8*)((const char*)&S[bf][0][mh][0] + by);
            }
    };
    auto LDB = [&](int bf, int nh, bf16x8 (&Bf)[2][2]) {
#pragma unroll
        for (int j = 0; j < 2; j++)
#pragma unroll
            for (int kh = 0; kh < 2; kh++) {
                const int by = swz128(((wc * 32 + j * 16 + lr) << 7) + (kh << 6) + (lc << 4));
                Bf[j][kh] = *(const bf16x8*)((const char*)&S[bf][1][nh][0] + by);
            }
    };
    auto QUAD = [&](f32x4 (&ac)[4][2], bf16x8 (&Bf)[2][2]) {
        __builtin_amdgcn_s_setprio(1);
#pragma unroll
        for (int i = 0; i < 4; i++)
#pragma unroll
            for (int j = 0; j < 2; j++)
#pragma unroll
                for (int kh = 0; kh < 2; kh++)
                    ac[i][j] = MFMA16(Af[i][kh], Bf[j][kh], ac[i][j]);
        __builtin_amdgcn_s_setprio(0);
    };

#define BAR() __builtin_amdgcn_s_barrier()
#define LGKM0() asm volatile("s_waitcnt lgkmcnt(0)" ::: "memory")

    // ---- prologue: tile0 (A0,A1,B0,B1)->buf0; A0[1],B1[1],A1[1]->buf1; drain to 3
    STAGE_A(0, 0, 0); STAGE_A(0, 1, 0); STAGE_B(0, 0, 0); STAGE_B(0, 1, 0);
    STAGE_A(1, 0, 1); STAGE_B(1, 1, 1); STAGE_A(1, 1, 1);
    asm volatile("s_waitcnt vmcnt(6)" ::: "memory");
    BAR();

    auto GROUP = [&](int g, int bf) {
        // ---- ph1: quadrant (0,0): read A0-chunk + B0-chunk; stage B0[g+1] -> other buf
        LDA(bf, 0); LDB(bf, 0, Bf0);
        if (g + 1 < QKV_NT) STAGE_B(bf ^ 1, 0, g + 1);
        BAR(); LGKM0();
        QUAD(acc[0][0], Bf0);
        BAR();
        // ---- ph2: (0,1): read B1-chunk (A kept); stage A0[g+2] -> current buf
        LDB(bf, 1, Bf1);
        if (g + 2 < QKV_NT) STAGE_A(bf, 0, g + 2);
        BAR(); LGKM0();
        QUAD(acc[0][1], Bf1);
        BAR();
        // ---- ph3: (1,1): read A1-chunk (B1 kept); stage B1[g+2] -> current buf
        LDA(bf, 1);
        if (g + 2 < QKV_NT) STAGE_B(bf, 1, g + 2);
        BAR(); LGKM0();
        QUAD(acc[1][1], Bf1);
        BAR();
        // ---- ph4: (1,0): no reads (A1,B0 kept); stage A1[g+2] -> current buf
        if (g + 2 < QKV_NT) STAGE_A(bf, 1, g + 2);
        BAR();
        QUAD(acc[1][0], Bf0);
        if (g == QKV_NT - 2) { asm volatile("s_waitcnt vmcnt(0)" ::: "memory"); }
        else                 { asm volatile("s_waitcnt vmcnt(6)" ::: "memory"); }
        BAR();
    };

#pragma unroll 1
    for (int g = 0; g < QKV_NT; g += 2) {
        GROUP(g, 0);
        GROUP(g + 1, 1);
    }

    // ---- epilogue: scatter into Q:(B,32,S,64), K/V:(B,8,S,64) bf16
#pragma unroll
    for (int mh = 0; mh < 2; mh++)
#pragma unroll
        for (int nh = 0; nh < 2; nh++)
#pragma unroll
            for (int i = 0; i < 4; i++)
#pragma unroll
                for (int j = 0; j < 2; j++) {
                    const int n = n0 + nh * 128 + wc * 32 + j * 16 + lr;
                    const int d = n & 63;
                    const int hh6 = n >> 6;
#pragma unroll
                    for (int r = 0; r < 4; r++) {
                        const int m = m0 + mh * 128 + wr * 64 + i * 16 + lc * 4 + r;
                        const int bb = m >> 11, s = m & 2047;
                        const unsigned short val = f2bf(acc[mh][nh][i][j][r]);
                        if (n < 2048) {
                            oq[((((size_t)bb * 32 + hh6) * 2048 + s) << 6) + d] = val;
                        } else if (n < 2560) {
                            ok[((((size_t)bb * 8 + (hh6 - 32)) * 2048 + s) << 6) + d] = val;
                        } else {
                            ov[((((size_t)bb * 8 + (hh6 - 40)) * 2048 + s) << 6) + d] = val;
                        }
                    }
                }
}
#undef BAR
#undef LGKM0

// ---------------------------------------------------------------- bt-GEMM (m97 structure + XCD swizzle) for out-proj
template <int EPI>
__global__ __launch_bounds__(256) void gemm_bt(
    const unsigned short* __restrict__ A,
    const unsigned short* __restrict__ B,
    int K, int N,
    unsigned short* __restrict__ oq,
    unsigned short* __restrict__ ok,
    unsigned short* __restrict__ ov,
    float* __restrict__ of)
{
    __shared__ __align__(16) unsigned short sA[128 * 32];
    __shared__ __align__(16) unsigned short sB[128 * 32];
    const int tid = threadIdx.x;
    const int lane = tid & 63, wave = tid >> 6;
    const int wr = wave >> 1, wc = wave & 1;
    const int lr = lane & 15, lc = lane >> 4;

    int bid = blockIdx.y * gridDim.x + blockIdx.x;
    const int cpx = (gridDim.x * gridDim.y) >> 3;
    bid = (bid & 7) * cpx + (bid >> 3);
    const int m0 = (bid / gridDim.x) * 128, n0 = (bid % gridDim.x) * 128;

    f32x4 acc[4][4];
#pragma unroll
    for (int i = 0; i < 4; i++)
#pragma unroll
        for (int j = 0; j < 4; j++) acc[i][j] = (f32x4){0.f, 0.f, 0.f, 0.f};

    const int u0 = tid, u1 = tid + 256;
    for (int k0 = 0; k0 < K; k0 += 32) {
        __syncthreads();
        gload_lds16(A + (size_t)(m0 + (u0 >> 2)) * K + k0 + (u0 & 3) * 8, &sA[u0 * 8]);
        gload_lds16(A + (size_t)(m0 + (u1 >> 2)) * K + k0 + (u1 & 3) * 8, &sA[u1 * 8]);
        gload_lds16(B + (size_t)(n0 + (u0 >> 2)) * K + k0 + (u0 & 3) * 8, &sB[u0 * 8]);
        gload_lds16(B + (size_t)(n0 + (u1 >> 2)) * K + k0 + (u1 & 3) * 8, &sB[u1 * 8]);
        __syncthreads();
        bf16x8 af[4], bfv[4];
#pragma unroll
        for (int i = 0; i < 4; i++) {
            af[i]  = *(const bf16x8*)&sA[(wr * 64 + i * 16 + lr) * 32 + lc * 8];
            bfv[i] = *(const bf16x8*)&sB[(wc * 64 + i * 16 + lr) * 32 + lc * 8];
        }
#pragma unroll
        for (int i = 0; i < 4; i++)
#pragma unroll
            for (int j = 0; j < 4; j++) acc[i][j] = MFMA16(af[i], bfv[j], acc[i][j]);
    }

    if (EPI == 0) {
#pragma unroll
        for (int i = 0; i < 4; i++) {
#pragma unroll
            for (int j = 0; j < 4; j++) {
                const int n = n0 + wc * 64 + j * 16 + lr;
                const int d = n & 63;
#pragma unroll
                for (int r = 0; r < 4; r++) {
                    const int m = m0 + wr * 64 + i * 16 + lc * 4 + r;
                    const int bb = m >> 11, s = m & 2047;
                    const unsigned short val = f2bf(acc[i][j][r]);
                    if (n < 2048) {
                        const int hh = n >> 6;
                        oq[((((size_t)bb * 32 + hh) * 2048 + s) << 6) + d] = val;
                    } else if (n < 2560) {
                        const int hh = (n >> 6) - 32;
                        ok[((((size_t)bb * 8 + hh) * 2048 + s) << 6) + d] = val;
                    } else {
                        const int hh = (n >> 6) - 40;
                        ov[((((size_t)bb * 8 + hh) * 2048 + s) << 6) + d] = val;
                    }
                }
            }
        }
    } else {
#pragma unroll
        for (int i = 0; i < 4; i++)
#pragma unroll
            for (int j = 0; j < 4; j++)
#pragma unroll
                for (int r = 0; r < 4; r++) {
                    const int m = m0 + wr * 64 + i * 16 + lc * 4 + r;
                    const int n = n0 + wc * 64 + j * 16 + lr;
                    of[(size_t)m * N + n] = acc[i][j][r];
                }
    }
}

// ---------------------------------------------------------------- RoPE (in-place on Q and K, bf16)
__global__ void rope_kernel(unsigned short* __restrict__ Qb,
                            unsigned short* __restrict__ Kb,
                            const float* __restrict__ fc)
{
    const int NQ = 2 * 32 * 2048 * 32;
    int i = blockIdx.x * 256 + threadIdx.x;
    unsigned short* base;
    if (i < NQ) base = Qb;
    else { base = Kb; i -= NQ; }
    const int p = i & 31, s = (i >> 5) & 2047, bh = i >> 16;
    const size_t off = (((size_t)bh * 2048 + s) << 6) + p * 2;
    const unsigned int w = *(const unsigned int*)&base[off];
    const float t0 = bf2f((unsigned short)(w & 0xffffu));
    const float t1 = bf2f((unsigned short)(w >> 16));
    const float c = fc[(s * 32 + p) * 2], sn = fc[(s * 32 + p) * 2 + 1];
    *(unsigned int*)&base[off] = pack_bf2(t0 * c - t1 * sn, t0 * sn + t1 * c);
}

// ---------------------------------------------------------------- flash attention v3 (unchanged, verified)
__global__ __launch_bounds__(256) void attn_kernel(
    const unsigned short* __restrict__ Q,
    const unsigned short* __restrict__ K,
    const unsigned short* __restrict__ V,
    const int* __restrict__ dstart,
    unsigned short* __restrict__ AO)
{
    const int qt = 31 - blockIdx.x; // heavy blocks first
    const int h = blockIdx.y, b = blockIdx.z;
    const int kvh = h >> 2;
    const int tid = threadIdx.x, lane = tid & 63, wave = tid >> 6;
    const int lr = lane & 15, lc = lane >> 4;
    const int q0 = qt * 64;
    const int qw = q0 + wave * 16;

    __shared__ __align__(16) unsigned short sK[64 * 64];   // chunk-XOR swizzled
    __shared__ __align__(16) unsigned short sVt[64][72];   // V^T, conflict-free writes

    const unsigned short* Qh = Q + (((size_t)b * 32 + h) * 2048) * 64;
    const unsigned short* Kh = K + (((size_t)b * 8 + kvh) * 2048) * 64;
    const unsigned short* Vh = V + (((size_t)b * 8 + kvh) * 2048) * 64;

    const bf16x8 qf0 = *(const bf16x8*)&Qh[(size_t)(qw + lr) * 64 + lc * 8];
    const bf16x8 qf1 = *(const bf16x8*)&Qh[(size_t)(qw + lr) * 64 + 32 + lc * 8];

    const int qglob = qw + lr;
    const int dsl = dstart[b * 2048 + qglob];
    const int ds_wmin = dstart[b * 2048 + qw];
    const int t0 = dstart[b * 2048 + q0] & ~63;

    float mrow = -1e30f, lrow = 0.f;
    f32x4 oacc[4];
#pragma unroll
    for (int j = 0; j < 4; j++) oacc[j] = (f32x4){0.f, 0.f, 0.f, 0.f};

    for (int t = t0; t < q0 + 64; t += 64) {
        __syncthreads();
        {
            int slot = tid;
            int r = slot >> 3, c = slot & 7;
            gload_lds16(Kh + (size_t)(t + r) * 64 + ((c ^ (r & 7)) * 8), &sK[slot * 8]);
            slot = tid + 256; r = slot >> 3; c = slot & 7;
            gload_lds16(Kh + (size_t)(t + r) * 64 + ((c ^ (r & 7)) * 8), &sK[slot * 8]);
        }
        {
            const int w8 = wave * 8;
            const uint4 va = *(const uint4*)&Vh[(size_t)(t + lane) * 64 + w8];
            const uint4 vb = *(const uint4*)&Vh[(size_t)(t + lane) * 64 + 32 + w8];
            const unsigned short* pa = (const unsigned short*)&va;
            const unsigned short* pb = (const unsigned short*)&vb;
#pragma unroll
            for (int e = 0; e < 8; e++) sVt[w8 + e][lane] = pa[e];
#pragma unroll
            for (int e = 0; e < 8; e++) sVt[32 + w8 + e][lane] = pb[e];
        }
        asm volatile("s_waitcnt vmcnt(0)" ::: "memory");
        __syncthreads();
        if (t > qw + 15 || t + 63 < ds_wmin) continue;

        f32x4 sc[4];
#pragma unroll
        for (int kk = 0; kk < 4; kk++) {
            const int krow = kk * 16 + lr;
            const bf16x8 kf0 = *(const bf16x8*)&sK[krow * 64 + ((lc ^ (lr & 7)) * 8)];
            const bf16x8 kf1 = *(const bf16x8*)&sK[krow * 64 + (((4 + lc) ^ (lr & 7)) * 8)];
            f32x4 a = (f32x4){0.f, 0.f, 0.f, 0.f};
            a = MFMA16(kf0, qf0, a);
            a = MFMA16(kf1, qf1, a);
            sc[kk] = a;
        }
        float vmax = -3e38f;
#pragma unroll
        for (int kk = 0; kk < 4; kk++)
#pragma unroll
            for (int r = 0; r < 4; r++) {
                const int kpos = t + kk * 16 + lc * 4 + r;
                const bool okm = (kpos <= qglob) && (kpos >= dsl);
                sc[kk][r] = okm ? sc[kk][r] * 0.125f : -3e38f;
                vmax = fmaxf(vmax, sc[kk][r]);
            }
        vmax = fmaxf(vmax, __shfl_xor(vmax, 16));
        vmax = fmaxf(vmax, __shfl_xor(vmax, 32));
        const float mnew = fmaxf(mrow, vmax);
        const float corr = __expf(mrow - mnew);
        mrow = mnew;

        float rsum = 0.f;
        unsigned int pk[4][2];
#pragma unroll
        for (int kk = 0; kk < 4; kk++) {
            const float p0 = __expf(sc[kk][0] - mnew);
            const float p1 = __expf(sc[kk][1] - mnew);
            const float p2 = __expf(sc[kk][2] - mnew);
            const float p3 = __expf(sc[kk][3] - mnew);
            rsum += (p0 + p1) + (p2 + p3);
            pk[kk][0] = pack_bf2(p0, p1);
            pk[kk][1] = pack_bf2(p2, p3);
        }
        rsum += __shfl_xor(rsum, 16);
        rsum += __shfl_xor(rsum, 32);
        lrow = lrow * corr + rsum;
#pragma unroll
        for (int j = 0; j < 4; j++)
#pragma unroll
            for (int r = 0; r < 4; r++) oacc[j][r] *= corr;

        const int srcEven = 32 * (lc & 1) + lr;
        const int srcOdd  = srcEven + 16;
        const bool hiKK = (lc & 2) != 0;
        union { unsigned int w[4]; bf16x8 v; } B0, B1;
        {
            unsigned int a, c;
            a = __shfl(pk[0][0], srcEven); c = __shfl(pk[1][0], srcEven); B0.w[0] = hiKK ? c : a;
            a = __shfl(pk[0][1], srcEven); c = __shfl(pk[1][1], srcEven); B0.w[1] = hiKK ? c : a;
            a = __shfl(pk[0][0], srcOdd);  c = __shfl(pk[1][0], srcOdd);  B0.w[2] = hiKK ? c : a;
            a = __shfl(pk[0][1], srcOdd);  c = __shfl(pk[1][1], srcOdd);  B0.w[3] = hiKK ? c : a;
            a = __shfl(pk[2][0], srcEven); c = __shfl(pk[3][0], srcEven); B1.w[0] = hiKK ? c : a;
            a = __shfl(pk[2][1], srcEven); c = __shfl(pk[3][1], srcEven); B1.w[1] = hiKK ? c : a;
            a = __shfl(pk[2][0], srcOdd);  c = __shfl(pk[3][0], srcOdd);  B1.w[2] = hiKK ? c : a;
            a = __shfl(pk[2][1], srcOdd);  c = __shfl(pk[3][1], srcOdd);  B1.w[3] = hiKK ? c : a;
        }

#pragma unroll
        for (int j = 0; j < 4; j++) {
            const bf16x8 a0 = *(const bf16x8*)&sVt[j * 16 + lr][lc * 8];
            const bf16x8 a1 = *(const bf16x8*)&sVt[j * 16 + lr][32 + lc * 8];
            oacc[j] = MFMA16(a0, B0.v, oacc[j]);
            oacc[j] = MFMA16(a1, B1.v, oacc[j]);
        }
    }

    __syncthreads();
    const float inv = 1.0f / lrow;
#pragma unroll
    for (int j = 0; j < 4; j++)
#pragma unroll
        for (int p = 0; p < 2; p++) {
            const unsigned int w = pack_bf2(oacc[j][2 * p] * inv, oacc[j][2 * p + 1] * inv);
            *(unsigned int*)&sVt[wave * 16 + lr][j * 16 + lc * 4 + 2 * p] = w;
        }
    __syncthreads();
#pragma unroll
    for (int half = 0; half < 2; half++) {
        const int c = lane + 64 * half;
        const int row = c >> 3, ch = c & 7;
        const uint4 o = *(const uint4*)&sVt[wave * 16 + row][ch * 8];
        *(uint4*)&AO[((size_t)b * 2048 + qw + row) * 2048 + h * 64 + ch * 8] = o;
    }
}

// ---------------------------------------------------------------- host
extern "C" void kernel_launch(void* const* d_in, const int* in_sizes, int n_in,
                              void* d_out, int out_size, void* d_ws, size_t ws_size,
                              hipStream_t stream) {
    const float* x  = (const float*)d_in[0];
    const float* fc = (const float*)d_in[1];
    const int* sid  = (const int*)d_in[2];
    const float* wq = (const float*)d_in[3];
    const float* wk = (const float*)d_in[4];
    const float* wv = (const float*)d_in[5];
    const float* wo = (const float*)d_in[6];
    float* out = (float*)d_out;

    unsigned short* xb   = (unsigned short*)d_ws;
    unsigned short* wqkv = xb + (size_t)4096 * 2048;
    unsigned short* wob  = wqkv + (size_t)3072 * 2048;
    unsigned short* Qb   = wob + (size_t)2048 * 2048;
    unsigned short* Kb   = Qb + (size_t)2 * 32 * 2048 * 64;
    unsigned short* Vb   = Kb + (size_t)2 * 8 * 2048 * 64;
    unsigned short* AO   = Vb + (size_t)2 * 8 * 2048 * 64;
    int* dstart = (int*)(AO + (size_t)4096 * 2048);

    cvt_kernel<<<8192, 256, 0, stream>>>(x, xb, 2097152);
    cvt_kernel<<<4096, 256, 0, stream>>>(wq, wqkv, 1048576);
    cvt_kernel<<<1024, 256, 0, stream>>>(wk, wqkv + (size_t)2048 * 2048, 262144);
    cvt_kernel<<<1024, 256, 0, stream>>>(wv, wqkv + (size_t)2560 * 2048, 262144);
    cvt_kernel<<<4096, 256, 0, stream>>>(wo, wob, 1048576);
    docstart_kernel<<<16, 256, 0, stream>>>(sid, dstart);
    gemm_qkv8<<<dim3(192), 512, 0, stream>>>(xb, wqkv, Qb, Kb, Vb);
    rope_kernel<<<20480, 256, 0, stream>>>(Qb, Kb, fc);
    attn_kernel<<<dim3(32, 32, 2), 256, 0, stream>>>(Qb, Kb, Vb, dstart, AO);
    gemm_bt<1><<<dim3(16, 32), 256, 0, stream>>>(AO, wob, 2048, 2048, nullptr, nullptr, nullptr, out);
}